// Round 9
// baseline (370.296 us; speedup 1.0000x reference)
//
#include <hip/hip_runtime.h>
#include <hip/hip_bf16.h>
#include <hip/hip_cooperative_groups.h>

// SelfAttentionTransformer: B=4, L=2048, D=256, H=8, dk=32, F=1024
// f32 inputs / f32 output. Round 9: cooperative mega-kernel (grid 256,
// occupancy>=1 guaranteed) with CHECKED launch + fallback to the validated
// R7 6-kernel chain (same device unit functions, single-source).

#define B_ 4
#define L_ 2048
#define D_ 256
#define F_ 1024
#define PI_F 3.14159265358979323846f

namespace cg = cooperative_groups;

typedef __bf16 bf16x8 __attribute__((ext_vector_type(8)));
typedef float floatx4 __attribute__((ext_vector_type(4)));

__device__ __forceinline__ unsigned short f2bf(float f) {
    unsigned int u = __float_as_uint(f);
    u = (u + 0x7FFFu + ((u >> 16) & 1u)) >> 16;   // RNE
    return (unsigned short)u;
}
__device__ __forceinline__ float bf2f(unsigned short u) {
    union { unsigned int i; float f; } v; v.i = ((unsigned int)u) << 16; return v.f;
}

__device__ __forceinline__ void async_cp16(unsigned short* lds, const unsigned short* g) {
    __builtin_amdgcn_global_load_lds(
        (const __attribute__((address_space(1))) unsigned int*)g,
        (__attribute__((address_space(3))) unsigned int*)lds, 16, 0, 0);
}

#define SMEM_BYTES 37376

// ---------------- P1: prep unit ----------------
__device__ __forceinline__ void prep_unit(int r, char* smem,
                                          const float* __restrict__ x,
                                          const float* __restrict__ W1,
                                          const float* __restrict__ W2,
                                          const int* __restrict__ mask,
                                          unsigned short* __restrict__ mb,
                                          unsigned short* __restrict__ XmT,
                                          unsigned short* __restrict__ W1T,
                                          unsigned short* __restrict__ W2T) {
    float* tile = (float*)smem;   // [32][33]
    int t = threadIdx.x;
    if (r >= 2560) {
        if (r < 2816) {
            int idx = (r - 2560) * 256 + t;
            int l = idx >> 5, k = idx & 31;
            float s = 0.f;
#pragma unroll
            for (int b = 0; b < B_; b++) {
                const float* xp = x + ((size_t)(b * L_ + l)) * D_ + k;
#pragma unroll
                for (int h = 0; h < 8; h++) s += xp[h * 32];
            }
            mb[idx] = f2bf(s * (1.f / 32.f));
        } else {
#pragma unroll
            for (int c = 0; c < 32; c++) {
                int e = c * 256 + t;
                int b = e >> 11, j = e & (L_ - 1);
                XmT[(size_t)(1024 + b) * L_ + j] = mask[b * L_ + j] ? 0x3F80 : 0;
            }
        }
        return;
    }
    const float* in; unsigned short* outp; int R, C; const int* mrow = nullptr; size_t bo = 0;
    int bx, by;
    if (r < 2048) {
        int z = r >> 9, rem = r & 511; by = rem >> 3; bx = rem & 7;
        in = x; outp = XmT; R = L_; C = 256; bo = (size_t)z * R * C; mrow = mask + z * L_;
    } else if (r < 2304) {
        int rem = r - 2048; bx = rem & 31; by = rem >> 5;
        in = W1; outp = W1T; R = 256; C = 1024;
    } else {
        int rem = r - 2304; bx = rem & 7; by = rem >> 3;
        in = W2; outp = W2T; R = 1024; C = 256;
    }
    int r0 = by * 32, c0 = bx * 32;
    int tx = t & 31, ty = t >> 5;
    __syncthreads();
#pragma unroll
    for (int rr = 0; rr < 4; rr++) {
        int rw = ty + rr * 8;
        tile[rw * 33 + tx] = in[bo + (size_t)(r0 + rw) * C + c0 + tx];
    }
    float mfac = 1.f;
    if (mrow) mfac = mrow[r0 + tx] ? 1.f : 0.f;
    __syncthreads();
#pragma unroll
    for (int rr = 0; rr < 4; rr++) {
        int c = ty + rr * 8;
        outp[bo + (size_t)(c0 + c) * R + r0 + tx] = f2bf(tile[tx * 33 + c] * mfac);
    }
}

// ---------------- P2: scores unit ----------------
__device__ __forceinline__ void scores_unit(int u, const unsigned short* __restrict__ mb,
                                            unsigned short* __restrict__ E) {
    const int t = threadIdx.x, lane = t & 63, wid = t >> 6;
    const int wm = (wid >> 1) * 64, wn = (wid & 1) * 32;
    const int lr = lane & 15, lq = lane >> 4;
    int m0 = (u >> 5) * 128, n0 = (u & 31) * 64;
    bf16x8 af[4], bfr[2];
#pragma unroll
    for (int i = 0; i < 4; i++)
        af[i] = *(const bf16x8*)(mb + (size_t)(m0 + wm + i * 16 + lr) * 32 + lq * 8);
#pragma unroll
    for (int j = 0; j < 2; j++)
        bfr[j] = *(const bf16x8*)(mb + (size_t)(n0 + wn + j * 16 + lr) * 32 + lq * 8);
    floatx4 acc[4][2];
#pragma unroll
    for (int i = 0; i < 4; i++)
#pragma unroll
        for (int j = 0; j < 2; j++) {
            acc[i][j] = (floatx4){0.f, 0.f, 0.f, 0.f};
            acc[i][j] = __builtin_amdgcn_mfma_f32_16x16x32_bf16(af[i], bfr[j], acc[i][j], 0, 0, 0);
        }
#pragma unroll
    for (int i = 0; i < 4; i++)
#pragma unroll
        for (int j = 0; j < 2; j++)
#pragma unroll
            for (int r = 0; r < 4; r++) {
                int row = m0 + wm + i * 16 + lq * 4 + r;
                int col = n0 + wn + j * 16 + lr;
                float d = fminf(fmaxf(acc[i][j][r], -PI_F), PI_F);
                float sn = __sinf(0.5f * d);
                E[(size_t)row * L_ + col] = f2bf(__expf(sn * sn));
            }
}

// ---------------- shared 128x64 MFMA core ----------------
__device__ __forceinline__ void mfma_gemm_async(const unsigned short* __restrict__ A,
                                                const unsigned short* __restrict__ Bt,
                                                int K, int m0, int n0,
                                                unsigned short* sA, unsigned short* sB,
                                                floatx4 acc[4][2]) {
    const int t = threadIdx.x;
    const int lane = t & 63, wid = t >> 6;
    const int wm = (wid >> 1) * 64, wn = (wid & 1) * 32;
    const int lr = lane & 15, lq = lane >> 4;
    const int lrow = lane >> 3, lseg = lane & 7;

    const unsigned short* Ag[4]; unsigned short* sAd[4];
#pragma unroll
    for (int q = 0; q < 4; q++) {
        int rl = wid * 32 + q * 8 + lrow;
        int seg = (lseg - rl) & 7;
        Ag[q] = A + (size_t)(m0 + rl) * K + seg * 8;
        sAd[q] = sA + (wid * 32 + q * 8) * 64;
    }
    const unsigned short* Bg[2]; unsigned short* sBd[2];
#pragma unroll
    for (int q = 0; q < 2; q++) {
        int rl = wid * 16 + q * 8 + lrow;
        int seg = (lseg - rl) & 7;
        Bg[q] = Bt + (size_t)(n0 + rl) * K + seg * 8;
        sBd[q] = sB + (wid * 16 + q * 8) * 64;
    }
    int arot[4], brot[2];
    const unsigned short* sAr[4]; const unsigned short* sBr[2];
#pragma unroll
    for (int i = 0; i < 4; i++) { int ar = wm + i * 16 + lr; sAr[i] = sA + ar * 64; arot[i] = lq + ar; }
#pragma unroll
    for (int j = 0; j < 2; j++) { int br = wn + j * 16 + lr; sBr[j] = sB + br * 64; brot[j] = lq + br; }

    for (int k0 = 0; k0 < K; k0 += 64) {
        __syncthreads();
#pragma unroll
        for (int q = 0; q < 4; q++) async_cp16(sAd[q], Ag[q] + k0);
#pragma unroll
        for (int q = 0; q < 2; q++) async_cp16(sBd[q], Bg[q] + k0);
        __syncthreads();
#pragma unroll
        for (int s = 0; s < 2; s++) {
            bf16x8 af[4], bfr[2];
#pragma unroll
            for (int i = 0; i < 4; i++)
                af[i] = *(const bf16x8*)(sAr[i] + ((s * 4 + arot[i]) & 7) * 8);
#pragma unroll
            for (int j = 0; j < 2; j++)
                bfr[j] = *(const bf16x8*)(sBr[j] + ((s * 4 + brot[j]) & 7) * 8);
#pragma unroll
            for (int i = 0; i < 4; i++)
#pragma unroll
                for (int j = 0; j < 2; j++)
                    acc[i][j] = __builtin_amdgcn_mfma_f32_16x16x32_bf16(af[i], bfr[j], acc[i][j], 0, 0, 0);
        }
    }
}

// ---------------- P3: AV unit ----------------
__device__ __forceinline__ void av_unit(int u, char* smem,
                                        const unsigned short* __restrict__ E,
                                        const unsigned short* __restrict__ XmT,
                                        unsigned short* __restrict__ Cb) {
    unsigned short* sA = (unsigned short*)smem;            // 16 KB
    unsigned short* sB = (unsigned short*)(smem + 16384);  // 8 KB
    floatx4 acc[4][2];
#pragma unroll
    for (int i = 0; i < 4; i++)
#pragma unroll
        for (int j = 0; j < 2; j++) acc[i][j] = (floatx4){0.f, 0.f, 0.f, 0.f};
    int m0 = (u / 17) * 128, n0 = (u % 17) * 64;
    mfma_gemm_async(E, XmT, L_, m0, n0, sA, sB, acc);
    const int lane = threadIdx.x & 63, wid = threadIdx.x >> 6;
    const int wm = (wid >> 1) * 64, wn = (wid & 1) * 32;
    const int lr = lane & 15, lq = lane >> 4;
#pragma unroll
    for (int i = 0; i < 4; i++)
#pragma unroll
        for (int j = 0; j < 2; j++)
#pragma unroll
            for (int r = 0; r < 4; r++) {
                int row = m0 + wm + i * 16 + lq * 4 + r;
                int col = n0 + wn + j * 16 + lr;
                Cb[(size_t)row * 1088 + col] = f2bf(acc[i][j][r]);
            }
}

// ---------------- P4: LN1 unit ----------------
__device__ __forceinline__ void ln1_unit(int tok, char* smem,
                                         const float* __restrict__ x, const unsigned short* __restrict__ Cb,
                                         const float* __restrict__ g_, const float* __restrict__ be_,
                                         unsigned short* __restrict__ hb) {
    float* sm = (float*)smem;   // 8 floats
    int t = threadIdx.x;
    int b = tok >> 11, i = tok & (L_ - 1);
    float rs = bf2f(Cb[(size_t)i * 1088 + 1024 + b]);
    float v = x[(size_t)tok * D_ + t] + bf2f(Cb[(size_t)i * 1088 + b * 256 + t]) / rs;
    float s = v, s2 = v * v;
#pragma unroll
    for (int o = 1; o < 64; o <<= 1) { s += __shfl_xor(s, o); s2 += __shfl_xor(s2, o); }
    __syncthreads();
    if ((t & 63) == 0) { sm[t >> 6] = s; sm[4 + (t >> 6)] = s2; }
    __syncthreads();
    s = sm[0] + sm[1] + sm[2] + sm[3];
    s2 = sm[4] + sm[5] + sm[6] + sm[7];
    float mu = s * (1.f / 256.f);
    float var = s2 * (1.f / 256.f) - mu * mu;
    float r = rsqrtf(var + 1e-5f);
    hb[(size_t)tok * D_ + t] = f2bf((v - mu) * r * g_[t] + be_[t]);
}

// ---------------- P5: GEMM1 unit ----------------
__device__ __forceinline__ void gemm1_unit(int u, char* smem,
                                           const unsigned short* __restrict__ hb,
                                           const unsigned short* __restrict__ W1T,
                                           const float* __restrict__ b1, unsigned short* __restrict__ t1) {
    unsigned short* sA = (unsigned short*)smem;            // 16 KB
    unsigned short* sB = (unsigned short*)(smem + 16384);  // 16 KB
    const int t = threadIdx.x, lane = t & 63, wid = t >> 6;
    const int wm = (wid >> 1) * 64, wn = (wid & 1) * 64;
    const int lr = lane & 15, lq = lane >> 4;
    const int lrow8 = lane >> 3, lseg = lane & 7;
    int m0 = (u >> 3) * 128, n0 = (u & 7) * 128;

    const unsigned short* Ag[4]; unsigned short* sAd[4];
    const unsigned short* Bg[4]; unsigned short* sBd[4];
#pragma unroll
    for (int q = 0; q < 4; q++) {
        int rl = q * 32 + wid * 8 + lrow8;
        int seg = (lseg - rl) & 7;
        Ag[q] = hb + (size_t)(m0 + rl) * 256 + seg * 8;
        Bg[q] = W1T + (size_t)(n0 + rl) * 256 + seg * 8;
        sAd[q] = sA + (q * 32 + wid * 8) * 64;
        sBd[q] = sB + (q * 32 + wid * 8) * 64;
    }
    const unsigned short* sAr[4]; int arot[4];
    const unsigned short* sBr[4]; int brot[4];
#pragma unroll
    for (int i = 0; i < 4; i++) { int ar = wm + i * 16 + lr; sAr[i] = sA + ar * 64; arot[i] = lq + ar; }
#pragma unroll
    for (int j = 0; j < 4; j++) { int br = wn + j * 16 + lr; sBr[j] = sB + br * 64; brot[j] = lq + br; }

    floatx4 acc[4][4];
#pragma unroll
    for (int i = 0; i < 4; i++)
#pragma unroll
        for (int j = 0; j < 4; j++) acc[i][j] = (floatx4){0.f, 0.f, 0.f, 0.f};

    for (int k0 = 0; k0 < 256; k0 += 64) {
        __syncthreads();
#pragma unroll
        for (int q = 0; q < 4; q++) { async_cp16(sAd[q], Ag[q] + k0); async_cp16(sBd[q], Bg[q] + k0); }
        __syncthreads();
#pragma unroll
        for (int s = 0; s < 2; s++) {
            bf16x8 af[4], bfr[4];
#pragma unroll
            for (int i = 0; i < 4; i++) af[i] = *(const bf16x8*)(sAr[i] + ((s * 4 + arot[i]) & 7) * 8);
#pragma unroll
            for (int j = 0; j < 4; j++) bfr[j] = *(const bf16x8*)(sBr[j] + ((s * 4 + brot[j]) & 7) * 8);
#pragma unroll
            for (int i = 0; i < 4; i++)
#pragma unroll
                for (int j = 0; j < 4; j++)
                    acc[i][j] = __builtin_amdgcn_mfma_f32_16x16x32_bf16(af[i], bfr[j], acc[i][j], 0, 0, 0);
        }
    }
    float bb[4];
#pragma unroll
    for (int j = 0; j < 4; j++) bb[j] = b1[n0 + wn + j * 16 + lr];
#pragma unroll
    for (int i = 0; i < 4; i++)
#pragma unroll
        for (int j = 0; j < 4; j++) {
            int col = n0 + wn + j * 16 + lr;
#pragma unroll
            for (int r = 0; r < 4; r++) {
                int row = m0 + wm + i * 16 + lq * 4 + r;
                t1[(size_t)row * 1024 + col] = f2bf(fmaxf(acc[i][j][r] + bb[j], 0.f));
            }
        }
}

// ---------------- P6: GEMM2+LN2 unit ----------------
__device__ __forceinline__ void gemm2ln_unit(int u, char* smem,
                                             const unsigned short* __restrict__ t1,
                                             const unsigned short* __restrict__ W2T,
                                             const float* __restrict__ b2,
                                             const unsigned short* __restrict__ hb,
                                             const float* __restrict__ g_, const float* __restrict__ be_,
                                             float* __restrict__ out) {
    unsigned short* sA = (unsigned short*)smem;            // 4 KB
    unsigned short* sB = (unsigned short*)(smem + 4096);   // 32 KB
    float* red = (float*)(smem + 36864);                   // 512 B
    const int t = threadIdx.x, lane = t & 63, wid = t >> 6;
    const int wm = (wid >> 1) * 16, wn = (wid & 1) * 128;
    const int lr = lane & 15, lq = lane >> 4;
    const int lrow8 = lane >> 3, lseg = lane & 7;
    int m0 = u * 32;

    int arl = wid * 8 + lrow8;
    const unsigned short* Ag = t1 + (size_t)(m0 + arl) * 1024 + (((lseg - arl) & 7) * 8);
    unsigned short* sAd = sA + (wid * 8) * 64;
    const unsigned short* Bg[8]; unsigned short* sBd[8];
#pragma unroll
    for (int q = 0; q < 8; q++) {
        int rl = q * 32 + wid * 8 + lrow8;
        Bg[q] = W2T + (size_t)rl * 1024 + (((lseg - rl) & 7) * 8);
        sBd[q] = sB + (q * 32 + wid * 8) * 64;
    }
    const unsigned short* sAr = sA + (wm + lr) * 64; int arot = lq + wm + lr;
    const unsigned short* sBr[8]; int brot[8];
#pragma unroll
    for (int j = 0; j < 8; j++) { int br = wn + j * 16 + lr; sBr[j] = sB + br * 64; brot[j] = lq + br; }

    floatx4 acc[8];
#pragma unroll
    for (int j = 0; j < 8; j++) acc[j] = (floatx4){0.f, 0.f, 0.f, 0.f};

    for (int k0 = 0; k0 < 1024; k0 += 64) {
        __syncthreads();
        async_cp16(sAd, Ag + k0);
#pragma unroll
        for (int q = 0; q < 8; q++) async_cp16(sBd[q], Bg[q] + k0);
        __syncthreads();
#pragma unroll
        for (int s = 0; s < 2; s++) {
            bf16x8 af = *(const bf16x8*)(sAr + ((s * 4 + arot) & 7) * 8);
#pragma unroll
            for (int j = 0; j < 8; j++) {
                bf16x8 bfr = *(const bf16x8*)(sBr[j] + ((s * 4 + brot[j]) & 7) * 8);
                acc[j] = __builtin_amdgcn_mfma_f32_16x16x32_bf16(af, bfr, acc[j], 0, 0, 0);
            }
        }
    }
    float psum[4], psq[4];
#pragma unroll
    for (int r = 0; r < 4; r++) { psum[r] = 0.f; psq[r] = 0.f; }
#pragma unroll
    for (int j = 0; j < 8; j++) {
        int col = wn + j * 16 + lr;
        float bv = b2[col];
#pragma unroll
        for (int r = 0; r < 4; r++) {
            int row = m0 + wm + lq * 4 + r;
            float v = acc[j][r] + bv + bf2f(hb[(size_t)row * 256 + col]);
            acc[j][r] = v;
            psum[r] += v; psq[r] += v * v;
        }
    }
#pragma unroll
    for (int o = 1; o < 16; o <<= 1) {
#pragma unroll
        for (int r = 0; r < 4; r++) { psum[r] += __shfl_xor(psum[r], o); psq[r] += __shfl_xor(psq[r], o); }
    }
    __syncthreads();
    if (lr == 0) {
#pragma unroll
        for (int r = 0; r < 4; r++) {
            int lrow = wm + lq * 4 + r;
            red[(((wid & 1) * 32) + lrow) * 2 + 0] = psum[r];
            red[(((wid & 1) * 32) + lrow) * 2 + 1] = psq[r];
        }
    }
    __syncthreads();
#pragma unroll
    for (int r = 0; r < 4; r++) {
        int lrow = wm + lq * 4 + r;
        float s = red[lrow * 2 + 0] + red[(32 + lrow) * 2 + 0];
        float s2 = red[lrow * 2 + 1] + red[(32 + lrow) * 2 + 1];
        float mu = s * (1.f / 256.f);
        float var = s2 * (1.f / 256.f) - mu * mu;
        float rc = rsqrtf(var + 1e-5f);
        int row = m0 + lrow;
#pragma unroll
        for (int j = 0; j < 8; j++) {
            int col = wn + j * 16 + lr;
            out[(size_t)row * 256 + col] = (acc[j][r] - mu) * rc * g_[col] + be_[col];
        }
    }
}

// ---------------- cooperative mega-kernel (grid 256) ----------------
__global__ __launch_bounds__(256) void k_mega(const float* __restrict__ x,
                                              const int* __restrict__ mask,
                                              const float* __restrict__ W1,
                                              const float* __restrict__ b1,
                                              const float* __restrict__ W2,
                                              const float* __restrict__ b2,
                                              const float* __restrict__ g1,
                                              const float* __restrict__ be1,
                                              const float* __restrict__ g2,
                                              const float* __restrict__ be2,
                                              float* __restrict__ out,
                                              char* __restrict__ ws) {
    __shared__ __align__(16) char smem[SMEM_BYTES];
    cg::grid_group grid = cg::this_grid();
    const int bid = blockIdx.x;

    unsigned short* mb_  = (unsigned short*)ws;
    unsigned short* E_   = (unsigned short*)(ws + 0x0020000);
    unsigned short* XmT_ = (unsigned short*)(ws + 0x0820000);
    unsigned short* W1T_ = (unsigned short*)(ws + 0x0C60000);
    unsigned short* W2T_ = (unsigned short*)(ws + 0x0CE0000);
    unsigned short* Cb_  = (unsigned short*)(ws + 0x0D60000);
    unsigned short* hb_  = (unsigned short*)(ws + 0x11A0000);
    unsigned short* t1_  = (unsigned short*)(ws + 0x15A0000);

#pragma unroll 1
    for (int u = bid; u < 2817; u += 256)
        prep_unit(u, smem, x, W1, W2, mask, mb_, XmT_, W1T_, W2T_);
    grid.sync();
#pragma unroll 1
    for (int u = bid; u < 512; u += 256)
        scores_unit(u, mb_, E_);
    grid.sync();
#pragma unroll 1
    for (int u = bid; u < 272; u += 256)
        av_unit(u, smem, E_, XmT_, Cb_);
    grid.sync();
#pragma unroll 1
    for (int it = 0; it < 32; it++)
        ln1_unit(it * 256 + bid, smem, x, Cb_, g1, be1, hb_);
    grid.sync();
#pragma unroll 1
    for (int u = bid; u < 512; u += 256)
        gemm1_unit(u, smem, hb_, W1T_, b1, t1_);
    grid.sync();
    gemm2ln_unit(bid, smem, t1_, W2T_, b2, hb_, g2, be2, out);
}

// ---------------- fallback wrappers (R7-equivalent chain) ----------------
__global__ __launch_bounds__(256) void k_prep_w(const float* x, const float* W1, const float* W2,
                                                const int* mask, unsigned short* mb, unsigned short* XmT,
                                                unsigned short* W1T, unsigned short* W2T) {
    __shared__ __align__(16) char smem[4352];
    prep_unit(blockIdx.x, smem, x, W1, W2, mask, mb, XmT, W1T, W2T);
}
__global__ __launch_bounds__(256) void k_scores_w(const unsigned short* mb, unsigned short* E) {
    scores_unit(blockIdx.x, mb, E);
}
__global__ __launch_bounds__(256) void k_av_w(const unsigned short* E, const unsigned short* XmT,
                                              unsigned short* Cb) {
    __shared__ __align__(16) char smem[24576];
    av_unit(blockIdx.x, smem, E, XmT, Cb);
}
__global__ __launch_bounds__(256) void k_ln1_w(const float* x, const unsigned short* Cb,
                                               const float* g1, const float* be1, unsigned short* hb) {
    __shared__ __align__(16) char smem[64];
    ln1_unit(blockIdx.x, smem, x, Cb, g1, be1, hb);
}
__global__ __launch_bounds__(256) void k_gemm1_w(const unsigned short* hb, const unsigned short* W1T,
                                                 const float* b1, unsigned short* t1) {
    __shared__ __align__(16) char smem[32768];
    gemm1_unit(blockIdx.x, smem, hb, W1T, b1, t1);
}
__global__ __launch_bounds__(256) void k_gemm2ln_w(const unsigned short* t1, const unsigned short* W2T,
                                                   const float* b2, const unsigned short* hb,
                                                   const float* g2, const float* be2, float* out) {
    __shared__ __align__(16) char smem[SMEM_BYTES];
    gemm2ln_unit(blockIdx.x, smem, t1, W2T, b2, hb, g2, be2, out);
}

extern "C" void kernel_launch(void* const* d_in, const int* in_sizes, int n_in,
                              void* d_out, int out_size, void* d_ws, size_t ws_size,
                              hipStream_t stream) {
    const float* x   = (const float*)d_in[0];
    const int*  mask = (const int*)d_in[1];
    const float* W1  = (const float*)d_in[2];
    const float* b1  = (const float*)d_in[3];
    const float* W2  = (const float*)d_in[4];
    const float* b2  = (const float*)d_in[5];
    const float* g1  = (const float*)d_in[6];
    const float* be1 = (const float*)d_in[7];
    const float* g2  = (const float*)d_in[8];
    const float* be2 = (const float*)d_in[9];
    float* out = (float*)d_out;
    char* ws = (char*)d_ws;

    unsigned short* mb_  = (unsigned short*)ws;
    unsigned short* E_   = (unsigned short*)(ws + 0x0020000);
    unsigned short* XmT_ = (unsigned short*)(ws + 0x0820000);
    unsigned short* W1T_ = (unsigned short*)(ws + 0x0C60000);
    unsigned short* W2T_ = (unsigned short*)(ws + 0x0CE0000);
    unsigned short* Cb_  = (unsigned short*)(ws + 0x0D60000);
    unsigned short* hb_  = (unsigned short*)(ws + 0x11A0000);
    unsigned short* t1_  = (unsigned short*)(ws + 0x15A0000);

    void* args[] = {(void*)&x, (void*)&mask, (void*)&W1, (void*)&b1, (void*)&W2, (void*)&b2,
                    (void*)&g1, (void*)&be1, (void*)&g2, (void*)&be2, (void*)&out, (void*)&ws};
    hipError_t e = hipLaunchCooperativeKernel((const void*)k_mega, dim3(256), dim3(256), args, 0, stream);
    if (e != hipSuccess) {
        (void)hipGetLastError();   // clear sticky error, take the validated chain
        k_prep_w<<<2817, 256, 0, stream>>>(x, W1, W2, mask, mb_, XmT_, W1T_, W2T_);
        k_scores_w<<<512, 256, 0, stream>>>(mb_, E_);
        k_av_w<<<272, 256, 0, stream>>>(E_, XmT_, Cb_);
        k_ln1_w<<<8192, 256, 0, stream>>>(x, Cb_, g1, be1, hb_);
        k_gemm1_w<<<512, 256, 0, stream>>>(hb_, W1T_, b1, t1_);
        k_gemm2ln_w<<<256, 256, 0, stream>>>(t1_, W2T_, b2, hb_, g2, be2, out);
    }
}

// Round 10
// 151.141 us; speedup vs baseline: 2.4500x; 2.4500x over previous
//
#include <hip/hip_runtime.h>
#include <hip/hip_bf16.h>

// SelfAttentionTransformer: B=4, L=2048, D=256, H=8, dk=32, F=1024
// f32 inputs / f32 output. Round 10: R7 validated 6-kernel chain;
// k_av upgraded to BK=128 (32 MFMA/barrier, 48KB LDS -> 3 blocks/CU).
// R9 established: harness fixed cost ~90us; coop mega-kernel rejected
// (1 blk/CU starvation: 280us vs chain ~60us GPU time).

#define B_ 4
#define L_ 2048
#define D_ 256
#define F_ 1024
#define PI_F 3.14159265358979323846f

typedef __bf16 bf16x8 __attribute__((ext_vector_type(8)));
typedef float floatx4 __attribute__((ext_vector_type(4)));

__device__ __forceinline__ unsigned short f2bf(float f) {
    unsigned int u = __float_as_uint(f);
    u = (u + 0x7FFFu + ((u >> 16) & 1u)) >> 16;   // RNE
    return (unsigned short)u;
}
__device__ __forceinline__ float bf2f(unsigned short u) {
    union { unsigned int i; float f; } v; v.i = ((unsigned int)u) << 16; return v.f;
}

__device__ __forceinline__ void async_cp16(unsigned short* lds, const unsigned short* g) {
    __builtin_amdgcn_global_load_lds(
        (const __attribute__((address_space(1))) unsigned int*)g,
        (__attribute__((address_space(3))) unsigned int*)lds, 16, 0, 0);
}

// ---------------- prep, compact 1D grid (2817 blocks) ----------------
__global__ __launch_bounds__(256) void k_prep(const float* __restrict__ x,
                                              const float* __restrict__ W1,
                                              const float* __restrict__ W2,
                                              const int* __restrict__ mask,
                                              unsigned short* __restrict__ mb,
                                              unsigned short* __restrict__ XmT,
                                              unsigned short* __restrict__ W1T,
                                              unsigned short* __restrict__ W2T) {
    __shared__ float tile[32][33];
    int r = blockIdx.x, t = threadIdx.x;
    if (r >= 2560) {
        if (r < 2816) {
            int idx = (r - 2560) * 256 + t;   // 0..65535
            int l = idx >> 5, k = idx & 31;
            float s = 0.f;
#pragma unroll
            for (int b = 0; b < B_; b++) {
                const float* xp = x + ((size_t)(b * L_ + l)) * D_ + k;
#pragma unroll
                for (int h = 0; h < 8; h++) s += xp[h * 32];
            }
            mb[idx] = f2bf(s * (1.f / 32.f));
        } else {
#pragma unroll
            for (int c = 0; c < 32; c++) {
                int e = c * 256 + t;          // 0..8191
                int b = e >> 11, j = e & (L_ - 1);
                XmT[(size_t)(1024 + b) * L_ + j] = mask[b * L_ + j] ? 0x3F80 : 0;
            }
        }
        return;
    }
    const float* in; unsigned short* outp; int R, C; const int* mrow = nullptr; size_t bo = 0;
    int bx, by;
    if (r < 2048) {
        int z = r >> 9, rem = r & 511; by = rem >> 3; bx = rem & 7;
        in = x; outp = XmT; R = L_; C = 256; bo = (size_t)z * R * C; mrow = mask + z * L_;
    } else if (r < 2304) {
        int rem = r - 2048; bx = rem & 31; by = rem >> 5;
        in = W1; outp = W1T; R = 256; C = 1024;
    } else {
        int rem = r - 2304; bx = rem & 7; by = rem >> 3;
        in = W2; outp = W2T; R = 1024; C = 256;
    }
    int r0 = by * 32, c0 = bx * 32;
    int tx = t & 31, ty = t >> 5;
#pragma unroll
    for (int rr = 0; rr < 4; rr++) {
        int rw = ty + rr * 8;
        tile[rw][tx] = in[bo + (size_t)(r0 + rw) * C + c0 + tx];
    }
    float mfac = 1.f;
    if (mrow) mfac = mrow[r0 + tx] ? 1.f : 0.f;
    __syncthreads();
#pragma unroll
    for (int rr = 0; rr < 4; rr++) {
        int c = ty + rr * 8;
        outp[bo + (size_t)(c0 + c) * R + r0 + tx] = f2bf(tile[tx][c] * mfac);
    }
}

// ---------------- E = exp(sin^2(0.5*clip(m.mT))) via MFMA, bf16 out ----------------
__global__ __launch_bounds__(256) void k_scores_mfma(const unsigned short* __restrict__ mb,
                                                     unsigned short* __restrict__ E) {
    const int t = threadIdx.x, lane = t & 63, wid = t >> 6;
    const int wm = (wid >> 1) * 64, wn = (wid & 1) * 32;
    const int lr = lane & 15, lq = lane >> 4;
    int m0 = blockIdx.y * 128, n0 = blockIdx.x * 64;
    bf16x8 af[4], bfr[2];
#pragma unroll
    for (int i = 0; i < 4; i++)
        af[i] = *(const bf16x8*)(mb + (size_t)(m0 + wm + i * 16 + lr) * 32 + lq * 8);
#pragma unroll
    for (int j = 0; j < 2; j++)
        bfr[j] = *(const bf16x8*)(mb + (size_t)(n0 + wn + j * 16 + lr) * 32 + lq * 8);
    floatx4 acc[4][2];
#pragma unroll
    for (int i = 0; i < 4; i++)
#pragma unroll
        for (int j = 0; j < 2; j++) {
            acc[i][j] = (floatx4){0.f, 0.f, 0.f, 0.f};
            acc[i][j] = __builtin_amdgcn_mfma_f32_16x16x32_bf16(af[i], bfr[j], acc[i][j], 0, 0, 0);
        }
#pragma unroll
    for (int i = 0; i < 4; i++)
#pragma unroll
        for (int j = 0; j < 2; j++)
#pragma unroll
            for (int r = 0; r < 4; r++) {
                int row = m0 + wm + i * 16 + lq * 4 + r;
                int col = n0 + wn + j * 16 + lr;
                float d = fminf(fmaxf(acc[i][j][r], -PI_F), PI_F);
                float sn = __sinf(0.5f * d);
                E[(size_t)row * L_ + col] = f2bf(__expf(sn * sn));
            }
}

// ---------------- AV: C[2048,1088] = E @ XmT^T, 128x64 tile, BK=128 ----------------
// LDS row = 128 elems (256B) = 16 segs of 16B, rotate swizzle seg' = (seg+row)&15.
__global__ __launch_bounds__(256) void k_av(const unsigned short* __restrict__ E,
                                            const unsigned short* __restrict__ XmT,
                                            unsigned short* __restrict__ Cb) {
    __shared__ __align__(16) unsigned short sA[128 * 128];   // 32 KB
    __shared__ __align__(16) unsigned short sB[64 * 128];    // 16 KB
    const int t = threadIdx.x, lane = t & 63, wid = t >> 6;
    const int wm = (wid >> 1) * 64, wn = (wid & 1) * 32;
    const int lr = lane & 15, lq = lane >> 4;
    const int lrow4 = lane >> 4, lseg = lane & 15;   // 4 rows x 16 segs per wave round
    int m0 = blockIdx.y * 128, n0 = blockIdx.x * 64;

    // A staging: 8 rounds x (4 rows/wave x 4 waves) = 128 rows
    const unsigned short* Ag[8]; unsigned short* sAd[8];
#pragma unroll
    for (int q = 0; q < 8; q++) {
        int rl = wid * 32 + q * 4 + lrow4;
        int seg = (lseg - rl) & 15;
        Ag[q] = E + (size_t)(m0 + rl) * L_ + seg * 8;
        sAd[q] = sA + (wid * 32 + q * 4) * 128;
    }
    // B staging: 4 rounds = 64 rows
    const unsigned short* Bg[4]; unsigned short* sBd[4];
#pragma unroll
    for (int q = 0; q < 4; q++) {
        int rl = wid * 16 + q * 4 + lrow4;
        int seg = (lseg - rl) & 15;
        Bg[q] = XmT + (size_t)(n0 + rl) * L_ + seg * 8;
        sBd[q] = sB + (wid * 16 + q * 4) * 128;
    }
    int arot[4], brot[2];
    const unsigned short* sAr[4]; const unsigned short* sBr[2];
#pragma unroll
    for (int i = 0; i < 4; i++) { int ar = wm + i * 16 + lr; sAr[i] = sA + ar * 128; arot[i] = lq + ar; }
#pragma unroll
    for (int j = 0; j < 2; j++) { int br = wn + j * 16 + lr; sBr[j] = sB + br * 128; brot[j] = lq + br; }

    floatx4 acc[4][2];
#pragma unroll
    for (int i = 0; i < 4; i++)
#pragma unroll
        for (int j = 0; j < 2; j++) acc[i][j] = (floatx4){0.f, 0.f, 0.f, 0.f};

    for (int k0 = 0; k0 < L_; k0 += 128) {
        __syncthreads();
#pragma unroll
        for (int q = 0; q < 8; q++) async_cp16(sAd[q], Ag[q] + k0);
#pragma unroll
        for (int q = 0; q < 4; q++) async_cp16(sBd[q], Bg[q] + k0);
        __syncthreads();
#pragma unroll
        for (int s = 0; s < 4; s++) {
            bf16x8 af[4], bfr[2];
#pragma unroll
            for (int i = 0; i < 4; i++)
                af[i] = *(const bf16x8*)(sAr[i] + ((s * 4 + arot[i]) & 15) * 8);
#pragma unroll
            for (int j = 0; j < 2; j++)
                bfr[j] = *(const bf16x8*)(sBr[j] + ((s * 4 + brot[j]) & 15) * 8);
#pragma unroll
            for (int i = 0; i < 4; i++)
#pragma unroll
                for (int j = 0; j < 2; j++)
                    acc[i][j] = __builtin_amdgcn_mfma_f32_16x16x32_bf16(af[i], bfr[j], acc[i][j], 0, 0, 0);
        }
    }
    const int wmE = wm, wnE = wn;
#pragma unroll
    for (int i = 0; i < 4; i++)
#pragma unroll
        for (int j = 0; j < 2; j++)
#pragma unroll
            for (int r = 0; r < 4; r++) {
                int row = m0 + wmE + i * 16 + lq * 4 + r;
                int col = n0 + wnE + j * 16 + lr;
                Cb[(size_t)row * 1088 + col] = f2bf(acc[i][j][r]);
            }
}

// ---------------- LN1 fused: v = x + C/rs; LN -> h bf16 ----------------
__global__ __launch_bounds__(256) void k_ln1(const float* __restrict__ x, const unsigned short* __restrict__ Cb,
                                             const float* __restrict__ g_, const float* __restrict__ be_,
                                             unsigned short* __restrict__ hb) {
    int tok = blockIdx.x, t = threadIdx.x;
    int b = tok >> 11, i = tok & (L_ - 1);
    float rs = bf2f(Cb[(size_t)i * 1088 + 1024 + b]);
    float v = x[(size_t)tok * D_ + t] + bf2f(Cb[(size_t)i * 1088 + b * 256 + t]) / rs;
    float s = v, s2 = v * v;
    __shared__ float sm[8];
#pragma unroll
    for (int o = 1; o < 64; o <<= 1) { s += __shfl_xor(s, o); s2 += __shfl_xor(s2, o); }
    if ((t & 63) == 0) { sm[t >> 6] = s; sm[4 + (t >> 6)] = s2; }
    __syncthreads();
    s = sm[0] + sm[1] + sm[2] + sm[3];
    s2 = sm[4] + sm[5] + sm[6] + sm[7];
    float mu = s * (1.f / 256.f);
    float var = s2 * (1.f / 256.f) - mu * mu;
    float r = rsqrtf(var + 1e-5f);
    hb[(size_t)tok * D_ + t] = f2bf((v - mu) * r * g_[t] + be_[t]);
}

// ---------------- GEMM1: t1 = relu(h @ W1 + b1) bf16; 128x128 tile, BK=64 ----------------
__global__ __launch_bounds__(256) void k_gemm1(const unsigned short* __restrict__ hb,
                                               const unsigned short* __restrict__ W1T,
                                               const float* __restrict__ b1, unsigned short* __restrict__ t1) {
    __shared__ __align__(16) unsigned short sA[128 * 64];
    __shared__ __align__(16) unsigned short sB[128 * 64];
    const int t = threadIdx.x, lane = t & 63, wid = t >> 6;
    const int wm = (wid >> 1) * 64, wn = (wid & 1) * 64;
    const int lr = lane & 15, lq = lane >> 4;
    const int lrow8 = lane >> 3, lseg = lane & 7;
    int m0 = blockIdx.y * 128, n0 = blockIdx.x * 128;

    const unsigned short* Ag[4]; unsigned short* sAd[4];
    const unsigned short* Bg[4]; unsigned short* sBd[4];
#pragma unroll
    for (int q = 0; q < 4; q++) {
        int rl = q * 32 + wid * 8 + lrow8;
        int seg = (lseg - rl) & 7;
        Ag[q] = hb + (size_t)(m0 + rl) * 256 + seg * 8;
        Bg[q] = W1T + (size_t)(n0 + rl) * 256 + seg * 8;
        sAd[q] = sA + (q * 32 + wid * 8) * 64;
        sBd[q] = sB + (q * 32 + wid * 8) * 64;
    }
    const unsigned short* sAr[4]; int arot[4];
    const unsigned short* sBr[4]; int brot[4];
#pragma unroll
    for (int i = 0; i < 4; i++) { int ar = wm + i * 16 + lr; sAr[i] = sA + ar * 64; arot[i] = lq + ar; }
#pragma unroll
    for (int j = 0; j < 4; j++) { int br = wn + j * 16 + lr; sBr[j] = sB + br * 64; brot[j] = lq + br; }

    floatx4 acc[4][4];
#pragma unroll
    for (int i = 0; i < 4; i++)
#pragma unroll
        for (int j = 0; j < 4; j++) acc[i][j] = (floatx4){0.f, 0.f, 0.f, 0.f};

    for (int k0 = 0; k0 < 256; k0 += 64) {
        __syncthreads();
#pragma unroll
        for (int q = 0; q < 4; q++) { async_cp16(sAd[q], Ag[q] + k0); async_cp16(sBd[q], Bg[q] + k0); }
        __syncthreads();
#pragma unroll
        for (int s = 0; s < 2; s++) {
            bf16x8 af[4], bfr[4];
#pragma unroll
            for (int i = 0; i < 4; i++) af[i] = *(const bf16x8*)(sAr[i] + ((s * 4 + arot[i]) & 7) * 8);
#pragma unroll
            for (int j = 0; j < 4; j++) bfr[j] = *(const bf16x8*)(sBr[j] + ((s * 4 + brot[j]) & 7) * 8);
#pragma unroll
            for (int i = 0; i < 4; i++)
#pragma unroll
                for (int j = 0; j < 4; j++)
                    acc[i][j] = __builtin_amdgcn_mfma_f32_16x16x32_bf16(af[i], bfr[j], acc[i][j], 0, 0, 0);
        }
    }
    float bb[4];
#pragma unroll
    for (int j = 0; j < 4; j++) bb[j] = b1[n0 + wn + j * 16 + lr];
#pragma unroll
    for (int i = 0; i < 4; i++)
#pragma unroll
        for (int j = 0; j < 4; j++) {
            int col = n0 + wn + j * 16 + lr;
#pragma unroll
            for (int r = 0; r < 4; r++) {
                int row = m0 + wm + i * 16 + lq * 4 + r;
                t1[(size_t)row * 1024 + col] = f2bf(fmaxf(acc[i][j][r] + bb[j], 0.f));
            }
        }
}

// ---------------- GEMM2+LN2 fused: out = LN(h + t1 @ W2 + b2), tile 32 x 256 ----------------
__global__ __launch_bounds__(256) void k_gemm2ln(const unsigned short* __restrict__ t1,
                                                 const unsigned short* __restrict__ W2T,
                                                 const float* __restrict__ b2,
                                                 const unsigned short* __restrict__ hb,
                                                 const float* __restrict__ g_, const float* __restrict__ be_,
                                                 float* __restrict__ out) {
    __shared__ __align__(16) unsigned short sA[32 * 64];    // 4 KB
    __shared__ __align__(16) unsigned short sB[256 * 64];   // 32 KB
    __shared__ float red[2][32][2];
    const int t = threadIdx.x, lane = t & 63, wid = t >> 6;
    const int wm = (wid >> 1) * 16, wn = (wid & 1) * 128;
    const int lr = lane & 15, lq = lane >> 4;
    const int lrow8 = lane >> 3, lseg = lane & 7;
    int m0 = blockIdx.x * 32;

    int arl = wid * 8 + lrow8;
    const unsigned short* Ag = t1 + (size_t)(m0 + arl) * 1024 + (((lseg - arl) & 7) * 8);
    unsigned short* sAd = sA + (wid * 8) * 64;
    const unsigned short* Bg[8]; unsigned short* sBd[8];
#pragma unroll
    for (int q = 0; q < 8; q++) {
        int rl = q * 32 + wid * 8 + lrow8;
        Bg[q] = W2T + (size_t)rl * 1024 + (((lseg - rl) & 7) * 8);
        sBd[q] = sB + (q * 32 + wid * 8) * 64;
    }
    const unsigned short* sAr = sA + (wm + lr) * 64; int arot = lq + wm + lr;
    const unsigned short* sBr[8]; int brot[8];
#pragma unroll
    for (int j = 0; j < 8; j++) { int br = wn + j * 16 + lr; sBr[j] = sB + br * 64; brot[j] = lq + br; }

    floatx4 acc[8];
#pragma unroll
    for (int j = 0; j < 8; j++) acc[j] = (floatx4){0.f, 0.f, 0.f, 0.f};

    for (int k0 = 0; k0 < 1024; k0 += 64) {
        __syncthreads();
        async_cp16(sAd, Ag + k0);
#pragma unroll
        for (int q = 0; q < 8; q++) async_cp16(sBd[q], Bg[q] + k0);
        __syncthreads();
#pragma unroll
        for (int s = 0; s < 2; s++) {
            bf16x8 af = *(const bf16x8*)(sAr + ((s * 4 + arot) & 7) * 8);
#pragma unroll
            for (int j = 0; j < 8; j++) {
                bf16x8 bfr = *(const bf16x8*)(sBr[j] + ((s * 4 + brot[j]) & 7) * 8);
                acc[j] = __builtin_amdgcn_mfma_f32_16x16x32_bf16(af, bfr, acc[j], 0, 0, 0);
            }
        }
    }
    float psum[4], psq[4];
#pragma unroll
    for (int r = 0; r < 4; r++) { psum[r] = 0.f; psq[r] = 0.f; }
#pragma unroll
    for (int j = 0; j < 8; j++) {
        int col = wn + j * 16 + lr;
        float bv = b2[col];
#pragma unroll
        for (int r = 0; r < 4; r++) {
            int row = m0 + wm + lq * 4 + r;
            float v = acc[j][r] + bv + bf2f(hb[(size_t)row * 256 + col]);
            acc[j][r] = v;
            psum[r] += v; psq[r] += v * v;
        }
    }
#pragma unroll
    for (int o = 1; o < 16; o <<= 1) {
#pragma unroll
        for (int r = 0; r < 4; r++) { psum[r] += __shfl_xor(psum[r], o); psq[r] += __shfl_xor(psq[r], o); }
    }
    if (lr == 0) {
#pragma unroll
        for (int r = 0; r < 4; r++) {
            int lrow = wm + lq * 4 + r;
            red[wid & 1][lrow][0] = psum[r];
            red[wid & 1][lrow][1] = psq[r];
        }
    }
    __syncthreads();
#pragma unroll
    for (int r = 0; r < 4; r++) {
        int lrow = wm + lq * 4 + r;
        float s = red[0][lrow][0] + red[1][lrow][0];
        float s2 = red[0][lrow][1] + red[1][lrow][1];
        float mu = s * (1.f / 256.f);
        float var = s2 * (1.f / 256.f) - mu * mu;
        float rc = rsqrtf(var + 1e-5f);
        int row = m0 + lrow;
#pragma unroll
        for (int j = 0; j < 8; j++) {
            int col = wn + j * 16 + lr;
            out[(size_t)row * 256 + col] = (acc[j][r] - mu) * rc * g_[col] + be_[col];
        }
    }
}

extern "C" void kernel_launch(void* const* d_in, const int* in_sizes, int n_in,
                              void* d_out, int out_size, void* d_ws, size_t ws_size,
                              hipStream_t stream) {
    const float* x   = (const float*)d_in[0];
    const int*  mask = (const int*)d_in[1];
    const float* W1  = (const float*)d_in[2];
    const float* b1  = (const float*)d_in[3];
    const float* W2  = (const float*)d_in[4];
    const float* b2  = (const float*)d_in[5];
    const float* g1  = (const float*)d_in[6];
    const float* be1 = (const float*)d_in[7];
    const float* g2  = (const float*)d_in[8];
    const float* be2 = (const float*)d_in[9];
    float* out = (float*)d_out;

    char* w = (char*)d_ws;
    unsigned short* mb_   = (unsigned short*)w;  w += 65536 * 2;                 // 128 KB
    unsigned short* E_    = (unsigned short*)w;  w += (size_t)L_ * L_ * 2;       // 8 MB
    unsigned short* XmT_  = (unsigned short*)w;  w += (size_t)1088 * L_ * 2;     // 4.25 MB
    unsigned short* W1T_  = (unsigned short*)w;  w += 262144 * 2;                // 512 KB
    unsigned short* W2T_  = (unsigned short*)w;  w += 262144 * 2;                // 512 KB
    unsigned short* Cb_   = (unsigned short*)w;  w += (size_t)L_ * 1088 * 2;     // 4.25 MB
    unsigned short* hb_   = (unsigned short*)w;  w += (size_t)8192 * 256 * 2;    // 4 MB
    unsigned short* t1_   = (unsigned short*)w;  w += (size_t)8192 * 1024 * 2;   // 16 MB

    k_prep<<<2817, 256, 0, stream>>>(x, W1, W2, mask, mb_, XmT_, W1T_, W2T_);
    k_scores_mfma<<<dim3(32, 16), 256, 0, stream>>>(mb_, E_);
    k_av<<<dim3(17, 16), 256, 0, stream>>>(E_, XmT_, Cb_);
    k_ln1<<<B_ * L_, 256, 0, stream>>>(x, Cb_, g1, be1, hb_);
    k_gemm1<<<dim3(8, 64), 256, 0, stream>>>(hb_, W1T_, b1, t1_);
    k_gemm2ln<<<256, 256, 0, stream>>>(t1_, W2T_, b2, hb_, g2, be2, out);
}